// Round 17
// baseline (316.405 us; speedup 1.0000x reference)
//
#include <hip/hip_runtime.h>
#include <hip/hip_bf16.h>

#define BB 8
#define CC 4096
#define DD 1024
#define EE 16
#define ESS 256
#define KSEL 4096
#define NTOK (BB*CC)
#define HLS 264   // padded Hl stride (shorts)

typedef short bf16x8 __attribute__((ext_vector_type(8)));
typedef float f32x4 __attribute__((ext_vector_type(4)));
typedef unsigned u32x4 __attribute__((ext_vector_type(4)));

struct PickRes { unsigned tau; unsigned n_gt; unsigned n_tie; float sm; };
struct Sel1 { unsigned b; unsigned above; unsigned kth; };

__device__ __forceinline__ short f2bf(float f) {
  unsigned u = __float_as_uint(f);
  u += 0x7FFFu + ((u >> 16) & 1u);
  return (short)(u >> 16);
}
__device__ __forceinline__ float bf2f(short s) {
  return __uint_as_float(((unsigned)(unsigned short)s) << 16);
}
__device__ __forceinline__ unsigned f2key(float f) {
  unsigned u = __float_as_uint(f);
  return (u & 0x80000000u) ? ~u : (u | 0x80000000u);
}

#define ASG __attribute__((address_space(1)))
#define ASL __attribute__((address_space(3)))
__device__ __forceinline__ void gl_lds16(void* l, const void* g) {
  __builtin_amdgcn_global_load_lds((ASG const unsigned*)g, (ASL unsigned*)l, 16, 0, 0);
}

// ---------------- K1: xsum + logits + x->bf16 conversion + inv init ----------------
__global__ void k_logits(const float* __restrict__ x, const float* __restrict__ gate,
                         float* __restrict__ logits, short* __restrict__ xb,
                         int* __restrict__ inv) {
  int wid = threadIdx.x >> 6, lane = threadIdx.x & 63;
  int t = blockIdx.x * 4 + wid;
  const float4* xr = reinterpret_cast<const float4*>(x + (size_t)t * DD);
  short4* xw = reinterpret_cast<short4*>(xb + (size_t)t * DD);
  float s = 0.f;
#pragma unroll
  for (int i = 0; i < 4; ++i) {
    float4 v = xr[lane + 64 * i];
    s += v.x + v.y + v.z + v.w;
    short4 p;
    p.x = f2bf(v.x); p.y = f2bf(v.y); p.z = f2bf(v.z); p.w = f2bf(v.w);
    xw[lane + 64 * i] = p;
  }
#pragma unroll
  for (int off = 32; off; off >>= 1) s += __shfl_xor(s, off);
  if (lane < EE) {
    int c = t & (CC - 1);
    logits[(size_t)lane * NTOK + t] = s * gate[c * EE + lane];
    inv[(size_t)t * EE + lane] = -1;
  }
}

// ---------------- k_hist ----------------
__global__ __launch_bounds__(1024) void k_hist(const float* __restrict__ logits,
                                               unsigned* __restrict__ ghist,
                                               float* __restrict__ separt) {
  int e = blockIdx.x & 15, seg = blockIdx.x >> 4;
  const float* L = logits + (size_t)e * NTOK + seg * 4096;
  unsigned* Hh = ghist + (size_t)e * 65536;
  int tid = threadIdx.x;
  float sl = 0.f;
#pragma unroll
  for (int i = 0; i < 4; ++i) {
    float lv = L[tid + 1024 * i];
    atomicAdd(&Hh[f2key(lv) >> 16], 1u);
    sl += expf(lv);
  }
  __shared__ float red[1024];
  red[tid] = sl; __syncthreads();
  for (int s2 = 512; s2; s2 >>= 1) {
    if (tid < s2) red[tid] += red[tid + s2];
    __syncthreads();
  }
  if (tid == 0) separt[e * 8 + seg] = red[0];
}

// ---------------- k_scan64k ----------------
__global__ __launch_bounds__(1024) void k_scan64k(
    const unsigned* __restrict__ hist, const Sel1* __restrict__ s1in, int phase,
    Sel1* __restrict__ s1out, const float* __restrict__ separt,
    PickRes* __restrict__ pres) {
  int e = blockIdx.x;
  const unsigned* Hh = hist + (size_t)e * 65536;
  int tid = threadIdx.x;
  __shared__ unsigned u0[1024], u1[1024];
  __shared__ unsigned sh_b, sh_above, sh_kth;
  unsigned target = (phase == 1) ? (unsigned)KSEL : s1in[e].kth;
  unsigned cs = 0;
  for (int j = 0; j < 64; ++j) cs += Hh[tid * 64 + j];
  u0[tid] = cs; __syncthreads();
  unsigned* src = u0; unsigned* dst = u1;
  for (int d2 = 1; d2 < 1024; d2 <<= 1) {
    unsigned v = src[tid] + ((tid + d2 < 1024) ? src[tid + d2] : 0u);
    dst[tid] = v; __syncthreads();
    unsigned* tmp = src; src = dst; dst = tmp;
  }
  unsigned above = (tid < 1023) ? src[tid + 1] : 0u;
  if (above < target && target <= src[tid]) {
    unsigned cum = above;
    for (int j = 63; j >= 0; --j) {
      unsigned h = Hh[tid * 64 + j];
      if (cum + h >= target) { sh_b = (unsigned)(tid * 64 + j); sh_above = cum; sh_kth = target - cum; break; }
      cum += h;
    }
  }
  __syncthreads();
  if (tid == 0) {
    if (phase == 1) {
      Sel1 s; s.b = sh_b; s.above = sh_above; s.kth = sh_kth;
      s1out[e] = s;
    } else {
      unsigned tau = (s1in[e].b << 16) | sh_b;
      unsigned n_gt = s1in[e].above + sh_above;
      float sm = 0.f;
      for (int j = 0; j < 8; ++j) sm += separt[e * 8 + j];
      PickRes pr; pr.tau = tau; pr.n_gt = n_gt; pr.n_tie = KSEL - n_gt; pr.sm = sm;
      pres[e] = pr;
    }
  }
}

// ---------------- k_refine ----------------
__global__ __launch_bounds__(1024) void k_refine(const float* __restrict__ logits,
                                                 const Sel1* __restrict__ s1,
                                                 unsigned* __restrict__ hist2) {
  int e = blockIdx.x & 15, seg = blockIdx.x >> 4;
  unsigned p16 = s1[e].b;
  const float* L = logits + (size_t)e * NTOK + seg * 4096;
  unsigned* Hh = hist2 + (size_t)e * 65536;
  int tid = threadIdx.x;
#pragma unroll
  for (int i = 0; i < 4; ++i) {
    unsigned key = f2key(L[tid + 1024 * i]);
    if ((key >> 16) == p16) atomicAdd(&Hh[key & 0xFFFF], 1u);
  }
}

// ---------------- k_count ----------------
__global__ __launch_bounds__(1024) void k_count(const float* __restrict__ logits,
                                                const PickRes* __restrict__ pres,
                                                unsigned* __restrict__ cnts) {
  int e = blockIdx.x & 15, seg = blockIdx.x >> 4;
  PickRes pr = pres[e];
  const float* L = logits + (size_t)e * NTOK + seg * 4096;
  int tid = threadIdx.x;
  unsigned pk = 0;
#pragma unroll
  for (int i = 0; i < 4; ++i) {
    unsigned key = f2key(L[tid + 1024 * i]);
    pk += (key > pr.tau) ? 0x10000u : ((key == pr.tau) ? 1u : 0u);
  }
  __shared__ unsigned red[1024];
  red[tid] = pk; __syncthreads();
  for (int s2 = 512; s2; s2 >>= 1) {
    if (tid < s2) red[tid] += red[tid + s2];
    __syncthreads();
  }
  if (tid == 0) cnts[e * 8 + seg] = red[0];   // (g<<16)|q
}

// ---------------- k_compact (derives its base from cnts) ----------------
__global__ __launch_bounds__(1024) void k_compact(const float* __restrict__ logits,
                                                  const PickRes* __restrict__ pres,
                                                  const unsigned* __restrict__ cnts,
                                                  int* __restrict__ sel_idx,
                                                  float* __restrict__ sel_val,
                                                  int* __restrict__ inv) {
  int e = blockIdx.x & 15, seg = blockIdx.x >> 4;
  PickRes pr = pres[e];
  const float* L = logits + (size_t)e * NTOK;
  __shared__ unsigned wtg[16], wtq[16];
  __shared__ unsigned base_g, base_q;
  int tid = threadIdx.x, wid = tid >> 6, lane = tid & 63;
  if (tid == 0) {
    unsigned gb = 0, qb = 0;
    for (int s = 0; s < seg; ++s) {
      unsigned c = cnts[e * 8 + s];
      gb += c >> 16; qb += c & 0xFFFFu;
    }
    base_g = gb; base_q = qb;
  }
  __syncthreads();
#pragma unroll 1
  for (int i = 0; i < 4; ++i) {
    int t = seg * 4096 + tid + 1024 * i;
    float lv = L[t];
    unsigned key = f2key(lv);
    bool g = key > pr.tau, q = key == pr.tau;
    unsigned long long bg = __ballot(g), bq = __ballot(q);
    unsigned long long lm = (1ull << lane) - 1ull;
    unsigned pg = __popcll(bg & lm), pq = __popcll(bq & lm);
    if (lane == 63) { wtg[wid] = pg + (g ? 1u : 0u); wtq[wid] = pq + (q ? 1u : 0u); }
    __syncthreads();
    unsigned og = base_g, oq = base_q;
    for (int w2 = 0; w2 < wid; ++w2) { og += wtg[w2]; oq += wtq[w2]; }
    unsigned slot = 0xFFFFFFFFu;
    if (g) slot = og + pg;
    else if (q) {
      unsigned r = oq + pq;
      if (r < pr.n_tie) slot = pr.n_gt + r;
    }
    if (slot != 0xFFFFFFFFu) {
      sel_idx[(size_t)e * KSEL + slot] = t;
      sel_val[(size_t)e * KSEL + slot] = expf(lv) / pr.sm;
      inv[(size_t)t * EE + e] = e * KSEL + (int)slot;
    }
    __syncthreads();
    if (tid == 0) {
      unsigned sg = 0, sq = 0;
#pragma unroll
      for (int w2 = 0; w2 < 16; ++w2) { sg += wtg[w2]; sq += wtq[w2]; }
      base_g += sg; base_q += sq;
    }
    __syncthreads();
  }
}

// ---------------- transpose ----------------
__global__ void k_transpose(const float* __restrict__ src, short* __restrict__ dst,
                            int R, int C) {
  __shared__ float tile[64][65];
  int c0 = blockIdx.x * 64, r0 = blockIdx.y * 64, b = blockIdx.z;
  const float* S = src + (size_t)b * R * C;
  short* Dp = dst + (size_t)b * R * C;
  int tx = threadIdx.x & 63, ty = threadIdx.x >> 6;
#pragma unroll
  for (int i = 0; i < 16; ++i) {
    int r = ty + 4 * i;
    tile[r][tx] = S[(size_t)(r0 + r) * C + c0 + tx];
  }
  __syncthreads();
#pragma unroll
  for (int i = 0; i < 16; ++i) {
    int cR = ty + 4 * i;
    Dp[(size_t)(c0 + cR) * R + r0 + tx] = f2bf(tile[tx][cR]);
  }
}

// ---------------- k_ff: FUSED expert FF, BM=64 (proven structure + Hl XOR + setprio) ----------------
// Hl col XOR: col ^= ((row>>3)&1)<<4 (16-short granule) on BOTH write and read.
// Makes write rows {r,r+4,r+8,r+12} land on disjoint bank octets (conflict-free);
// phase-2 b128 reads stay <=2-way; 16B alignment preserved.
__global__ __launch_bounds__(512, 2) void k_ff(
    const short* __restrict__ xb, const short* __restrict__ W1T,
    const short* __restrict__ W2T, const int* __restrict__ sel_idx,
    const float* __restrict__ sel_val, short* __restrict__ out) {
  int bid = blockIdx.x;
  int e = (bid & 7) + ((bid >> 9) << 3);      // expert -> XCD affinity
  int m0 = ((bid >> 3) & 63) * 64;
  __shared__ short Hl[64 * HLS];              // 33 KB
  __shared__ bf16x8 As8[64 * 8];              // 8 KB
  __shared__ bf16x8 Bs8[256 * 8];             // 32 KB (W1 then W2 staging)
  int tid = threadIdx.x, lane = tid & 63, wid = tid >> 6;
  int wr = wid >> 2, wc = wid & 3;            // 2 x 4 waves, wave tile 32x64
  const int* idxE = sel_idx + (size_t)e * KSEL;
  f32x4 acc[2][4] = {};

  int rowA = tid >> 3, sA = tid & 7;
  int xk = rowA & 7;
  const short* aSrc = xb + (size_t)idxE[m0 + rowA] * DD + (sA ^ xk) * 8;
  const short* w1Base = W1T + (size_t)e * ESS * DD + (size_t)rowA * DD + (sA ^ xk) * 8;
  const short* w2Base = W2T + (size_t)e * DD * ESS + (size_t)rowA * ESS + (sA ^ xk) * 8;

  // ---- phase 1: K = DD = 1024, 16 steps ----
  for (int kt = 0; kt < DD / 64; ++kt) {
    int kofs = kt * 64;
    gl_lds16(&As8[tid], aSrc + kofs);
#pragma unroll
    for (int j = 0; j < 4; ++j)
      gl_lds16(&Bs8[j * 512 + tid], w1Base + (size_t)(64 * j) * DD + kofs);
    __syncthreads();
    bf16x8 af[2][2];
#pragma unroll
    for (int mg = 0; mg < 2; ++mg) {
      int row = wr * 32 + mg * 16 + (lane & 15);
#pragma unroll
      for (int h = 0; h < 2; ++h) {
        int seg = h * 4 + (lane >> 4);
        af[mg][h] = As8[row * 8 + (seg ^ (row & 7))];
      }
    }
    __builtin_amdgcn_s_setprio(1);
#pragma unroll
    for (int ng = 0; ng < 4; ++ng) {
      int rowb = wc * 64 + ng * 16 + (lane & 15);
      bf16x8 b0 = Bs8[rowb * 8 + (((lane >> 4) + 0) ^ (rowb & 7))];
      bf16x8 b1 = Bs8[rowb * 8 + (((lane >> 4) + 4) ^ (rowb & 7))];
#pragma unroll
      for (int mg = 0; mg < 2; ++mg) {
        acc[mg][ng] = __builtin_amdgcn_mfma_f32_16x16x32_bf16(af[mg][0], b0, acc[mg][ng], 0, 0, 0);
        acc[mg][ng] = __builtin_amdgcn_mfma_f32_16x16x32_bf16(af[mg][1], b1, acc[mg][ng], 0, 0, 0);
      }
    }
    __builtin_amdgcn_s_setprio(0);
    __syncthreads();
  }
  // ---- prestage W2 (stage 0) while writing Hl ----
#pragma unroll
  for (int j = 0; j < 4; ++j)
    gl_lds16(&Bs8[j * 512 + tid], w2Base + (size_t)(64 * j) * ESS);
  // ---- H tile -> LDS (relu * val), XOR-banked ----
#pragma unroll
  for (int mg = 0; mg < 2; ++mg) {
#pragma unroll
    for (int r = 0; r < 4; ++r) {
      int hrow = wr * 32 + mg * 16 + (lane >> 4) * 4 + r;
      float v = sel_val[(size_t)e * KSEL + m0 + hrow];
      int rx = ((hrow >> 3) & 1) << 4;
#pragma unroll
      for (int ng = 0; ng < 4; ++ng) {
        int col = wc * 64 + ng * 16 + (lane & 15);
        Hl[hrow * HLS + (col ^ rx)] = f2bf(fmaxf(acc[mg][ng][r], 0.f) * v);
      }
    }
  }
  __syncthreads();   // Hl visible + stage(0) landed (barrier drains vmcnt)
  // ---- phase 2: 16 flattened stages (np = s>>2, kt = s&3); out-write overlaps staging ----
  f32x4 acc2[2][4] = {};
#pragma unroll 1
  for (int s = 0; s < 16; ++s) {
    int kt = s & 3;
    bf16x8 af[2][2];
#pragma unroll
    for (int mg = 0; mg < 2; ++mg) {
      int row = wr * 32 + mg * 16 + (lane & 15);
      int rx = ((row >> 3) & 1) << 4;
#pragma unroll
      for (int h = 0; h < 2; ++h) {
        int s8 = h * 4 + (lane >> 4);
        int colr = (kt * 64 + s8 * 8) ^ rx;
        af[mg][h] = *reinterpret_cast<const bf16x8*>(&Hl[row * HLS + colr]);
      }
    }
    __builtin_amdgcn_s_setprio(1);
#pragma unroll
    for (int ng = 0; ng < 4; ++ng) {
      int rowb = wc * 64 + ng * 16 + (lane & 15);
      bf16x8 b0 = Bs8[rowb * 8 + (((lane >> 4) + 0) ^ (rowb & 7))];
      bf16x8 b1 = Bs8[rowb * 8 + (((lane >> 4) + 4) ^ (rowb & 7))];
#pragma unroll
      for (int mg = 0; mg < 2; ++mg) {
        acc2[mg][ng] = __builtin_amdgcn_mfma_f32_16x16x32_bf16(af[mg][0], b0, acc2[mg][ng], 0, 0, 0);
        acc2[mg][ng] = __builtin_amdgcn_mfma_f32_16x16x32_bf16(af[mg][1], b1, acc2[mg][ng], 0, 0, 0);
      }
    }
    __builtin_amdgcn_s_setprio(0);
    __syncthreads();                       // all waves done reading Bs8
    if (s < 15) {                          // issue next W2 stage
      int s2 = s + 1;
      int np2 = s2 >> 2, kt2 = s2 & 3;
#pragma unroll
      for (int j = 0; j < 4; ++j)
        gl_lds16(&Bs8[j * 512 + tid],
                 w2Base + (size_t)(np2 * 256 + 64 * j) * ESS + kt2 * 64);
    }
    if (kt == 3) {                         // n-panel done: write out (overlaps stage)
      int np = s >> 2;
      int n0 = np * 256;
#pragma unroll
      for (int mg = 0; mg < 2; ++mg) {
#pragma unroll
        for (int r = 0; r < 4; ++r) {
          int ml = wr * 32 + mg * 16 + (lane >> 4) * 4 + r;
          short* orow = out + ((size_t)(e * KSEL + m0 + ml)) * DD + n0 + wc * 64 + (lane & 15);
#pragma unroll
          for (int ng = 0; ng < 4; ++ng) orow[ng * 16] = f2bf(acc2[mg][ng][r]);
        }
      }
#pragma unroll
      for (int mg = 0; mg < 2; ++mg)
#pragma unroll
        for (int ng = 0; ng < 4; ++ng) {
          f32x4 zz = {0.f, 0.f, 0.f, 0.f};
          acc2[mg][ng] = zz;
        }
    }
    if (s < 15) __syncthreads();           // next stage landed
  }
}

// ---------------- fallback GEMMs (atomic path, used only if workspace too small) ----------------
__global__ __launch_bounds__(512, 4) void k_gemm1(
    const short* __restrict__ xb, const short* __restrict__ W1T,
    const int* __restrict__ sel_idx, const float* __restrict__ sel_val,
    short* __restrict__ H) {
  int bid = blockIdx.x;
  int m0 = ((bid >> 3) & 31) * 128;
  int e = (bid & 7) + ((bid >> 8) << 3);
  __shared__ bf16x8 As8[128 * 8];
  __shared__ bf16x8 Bs8[256 * 8];
  int tid = threadIdx.x, lane = tid & 63, wid = tid >> 6;
  int wr = wid >> 2, wc = wid & 3;
  const int* idxE = sel_idx + (size_t)e * KSEL;
  f32x4 acc[4][4] = {};

  int rowA = tid >> 3, sA = tid & 7;
  int xk = rowA & 7;
  const short* aSrc0 = xb + (size_t)idxE[m0 + rowA] * DD + (sA ^ xk) * 8;
  const short* aSrc1 = xb + (size_t)idxE[m0 + rowA + 64] * DD + (sA ^ xk) * 8;
  const short* wBase = W1T + (size_t)e * ESS * DD + (size_t)rowA * DD + (sA ^ xk) * 8;

  for (int kt = 0; kt < DD / 64; ++kt) {
    int kofs = kt * 64;
    gl_lds16(&As8[tid], aSrc0 + kofs);
    gl_lds16(&As8[512 + tid], aSrc1 + kofs);
#pragma unroll
    for (int j = 0; j < 4; ++j)
      gl_lds16(&Bs8[j * 512 + tid], wBase + (size_t)(64 * j) * DD + kofs);
    __syncthreads();
    bf16x8 af[4][2];
#pragma unroll
    for (int mg = 0; mg < 4; ++mg) {
      int row = wr * 64 + mg * 16 + (lane & 15);
#pragma unroll
      for (int h = 0; h < 2; ++h) {
        int seg = h * 4 + (lane >> 4);
        af[mg][h] = As8[row * 8 + (seg ^ (row & 7))];
      }
    }
#pragma unroll
    for (int ng = 0; ng < 4; ++ng) {
      int rowb = wc * 64 + ng * 16 + (lane & 15);
      bf16x8 b0 = Bs8[rowb * 8 + (((lane >> 4) + 0) ^ (rowb & 7))];
      bf16x8 b1 = Bs8[rowb * 8 + (((lane >> 4) + 4) ^ (rowb & 7))];
#pragma unroll
      for (int mg = 0; mg < 4; ++mg) {
        acc[mg][ng] = __builtin_amdgcn_mfma_f32_16x16x32_bf16(af[mg][0], b0, acc[mg][ng], 0, 0, 0);
        acc[mg][ng] = __builtin_amdgcn_mfma_f32_16x16x32_bf16(af[mg][1], b1, acc[mg][ng], 0, 0, 0);
      }
    }
    __syncthreads();
  }
#pragma unroll
  for (int mg = 0; mg < 4; ++mg) {
#pragma unroll
    for (int r = 0; r < 4; ++r) {
      int ml = wr * 64 + mg * 16 + (lane >> 4) * 4 + r;
      float v = sel_val[(size_t)e * KSEL + m0 + ml];
      short* hrow = H + ((size_t)(e * KSEL + m0 + ml)) * ESS + wc * 64 + (lane & 15);
#pragma unroll
      for (int ng = 0; ng < 4; ++ng) {
        float o = fmaxf(acc[mg][ng][r], 0.f) * v;
        hrow[ng * 16] = f2bf(o);
      }
    }
  }
}

__global__ __launch_bounds__(512, 4) void k_gemm2_atomic(
    const short* __restrict__ H, const short* __restrict__ W2T,
    const int* __restrict__ sel_idx, float* __restrict__ z) {
  int bid = blockIdx.x;
  int p = (bid & 7) + ((bid >> 8) << 3);
  int m0 = ((bid >> 3) & 31) * 128;
  int n0 = (p & 3) * 256;
  int e = p >> 2;
  __shared__ bf16x8 As8[128 * 8];
  __shared__ bf16x8 Bs8[256 * 8];
  int tid = threadIdx.x, lane = tid & 63, wid = tid >> 6;
  int wr = wid >> 2, wc = wid & 3;
  f32x4 acc[4][4] = {};

  int rowA = tid >> 3, sA = tid & 7;
  int xk = rowA & 7;
  const short* hBase = H + (size_t)(e * KSEL + m0 + rowA) * ESS + (sA ^ xk) * 8;
  const short* w2Base = W2T + (size_t)(e * DD + n0 + rowA) * ESS + (sA ^ xk) * 8;

  for (int kt = 0; kt < ESS / 64; ++kt) {
    int kofs = kt * 64;
    gl_lds16(&As8[tid], hBase + kofs);
    gl_lds16(&As8[512 + tid], hBase + (size_t)64 * ESS + kofs);
#pragma unroll
    for (int j = 0; j < 4; ++j)
      gl_lds16(&Bs8[j * 512 + tid], w2Base + (size_t)(64 * j) * ESS + kofs);
    __syncthreads();
    bf16x8 af[4][2];
#pragma unroll
    for (int mg = 0; mg < 4; ++mg) {
      int row = wr * 64 + mg * 16 + (lane & 15);
#pragma unroll
      for (int h = 0; h < 2; ++h) {
        int seg = h * 4 + (lane >> 4);
        af[mg][h] = As8[row * 8 + (seg ^ (row & 7))];
      }
    }
#pragma unroll
    for (int ng = 0; ng < 4; ++ng) {
      int rowb = wc * 64 + ng * 16 + (lane & 15);
      bf16x8 b0 = Bs8[rowb * 8 + (((lane >> 4) + 0) ^ (rowb & 7))];
      bf16x8 b1 = Bs8[rowb * 8 + (((lane >> 4) + 4) ^ (rowb & 7))];
#pragma unroll
      for (int mg = 0; mg < 4; ++mg) {
        acc[mg][ng] = __builtin_amdgcn_mfma_f32_16x16x32_bf16(af[mg][0], b0, acc[mg][ng], 0, 0, 0);
        acc[mg][ng] = __builtin_amdgcn_mfma_f32_16x16x32_bf16(af[mg][1], b1, acc[mg][ng], 0, 0, 0);
      }
    }
    __syncthreads();
  }
#pragma unroll
  for (int mg = 0; mg < 4; ++mg) {
#pragma unroll
    for (int r = 0; r < 4; ++r) {
      int ml = wr * 64 + mg * 16 + (lane >> 4) * 4 + r;
      int token = sel_idx[(size_t)e * KSEL + m0 + ml];
      float* zr = z + (size_t)token * DD + n0 + wc * 64 + (lane & 15);
#pragma unroll
      for (int ng = 0; ng < 4; ++ng) atomicAdd(zr + ng * 16, acc[mg][ng][r]);
    }
  }
}

// ---------------- combine: 2 tokens per wave ----------------
__global__ __launch_bounds__(256) void k_combine(const short* __restrict__ out,
                                                 const int* __restrict__ inv,
                                                 float* __restrict__ z) {
  int wid = threadIdx.x >> 6, lane = threadIdx.x & 63;
  int tA = (blockIdx.x * 4 + wid) * 2;
  int tB = tA + 1;
  int gA[16], gB[16];
  const int4* ivA = reinterpret_cast<const int4*>(inv + (size_t)tA * EE);
  const int4* ivB = reinterpret_cast<const int4*>(inv + (size_t)tB * EE);
#pragma unroll
  for (int q = 0; q < 4; ++q) {
    int4 va = ivA[q];
    gA[4 * q] = va.x; gA[4 * q + 1] = va.y; gA[4 * q + 2] = va.z; gA[4 * q + 3] = va.w;
    int4 vb = ivB[q];
    gB[4 * q] = vb.x; gB[4 * q + 1] = vb.y; gB[4 * q + 2] = vb.z; gB[4 * q + 3] = vb.w;
  }
  float accA[16] = {}, accB[16] = {};
#pragma unroll
  for (int e = 0; e < EE; ++e) {
    if (gA[e] >= 0) {
      const u32x4* rp = reinterpret_cast<const u32x4*>(out + (size_t)gA[e] * DD + lane * 16);
      u32x4 v0 = rp[0], v1 = rp[1];
      const short* s0 = reinterpret_cast<const short*>(&v0);
      const short* s1 = reinterpret_cast<const short*>(&v1);
#pragma unroll
      for (int i = 0; i < 8; ++i) { accA[i] += bf2f(s0[i]); accA[8 + i] += bf2f(s1[i]); }
    }
    if (gB[e] >= 0) {
      const u32x4* rp = reinterpret_cast<const u32x4*>(out + (size_t)gB[e] * DD + lane * 16);
      u32x4 v0 = rp[0], v1 = rp[1];
      const short* s0 = reinterpret_cast<const short*>(&v0);
      const short* s1 = reinterpret_cast<const short*>(&v1);
#pragma unroll
      for (int i = 0; i < 8; ++i) { accB[i] += bf2f(s0[i]); accB[8 + i] += bf2f(s1[i]); }
    }
  }
  float4* zwA = reinterpret_cast<float4*>(z + (size_t)tA * DD + lane * 16);
  float4* zwB = reinterpret_cast<float4*>(z + (size_t)tB * DD + lane * 16);
#pragma unroll
  for (int i = 0; i < 4; ++i) {
    float4 oa;
    oa.x = accA[4 * i]; oa.y = accA[4 * i + 1]; oa.z = accA[4 * i + 2]; oa.w = accA[4 * i + 3];
    zwA[i] = oa;
    float4 ob;
    ob.x = accB[4 * i]; ob.y = accB[4 * i + 1]; ob.z = accB[4 * i + 2]; ob.w = accB[4 * i + 3];
    zwB[i] = ob;
  }
}

extern "C" void kernel_launch(void* const* d_in, const int* in_sizes, int n_in,
                              void* d_out, int out_size, void* d_ws, size_t ws_size,
                              hipStream_t stream) {
  (void)in_sizes; (void)n_in;
  const float* x = (const float*)d_in[0];
  const float* gate = (const float*)d_in[1];
  const float* lin1 = (const float*)d_in[2];
  const float* lin2 = (const float*)d_in[3];
  float* z = (float*)d_out;

  char* ws = (char*)d_ws;
  size_t off = 0;
  auto alloc = [&](size_t bytes) -> void* {
    off = (off + 255) & ~(size_t)255;
    void* p = ws + off;
    off += bytes;
    return p;
  };
  float* logits = (float*)alloc((size_t)EE * NTOK * 4);
  int* sidx = (int*)alloc((size_t)EE * KSEL * 4);
  float* sval = (float*)alloc((size_t)EE * KSEL * 4);
  int* inv = (int*)alloc((size_t)NTOK * EE * 4);
  short* W1T = (short*)alloc((size_t)EE * ESS * DD * 2);
  short* W2T = (short*)alloc((size_t)EE * DD * ESS * 2);
  short* H = (short*)alloc((size_t)EE * KSEL * ESS * 2);
  short* xb = (short*)alloc((size_t)NTOK * DD * 2);
  size_t out_bytes = (size_t)EE * KSEL * DD * 2;
  bool combine = (off + 256 + out_bytes) <= ws_size;
  short* outbuf = combine ? (short*)alloc(out_bytes) : nullptr;

  // select scratch aliases H (H is only used by the fallback path, after select)
  unsigned* ghist = (unsigned*)H;                                    // 4 MB
  unsigned* hist2 = (unsigned*)((char*)H + (size_t)4 * 1024 * 1024); // 4 MB
  float* separt = (float*)((char*)H + (size_t)8 * 1024 * 1024);      // 512 B
  Sel1* s1 = (Sel1*)((char*)separt + 1024);                          // 256 B
  PickRes* pres = (PickRes*)((char*)s1 + 1024);                      // 256 B
  unsigned* cnts = (unsigned*)((char*)pres + 1024);                  // 512 B

  // weight transposes
  k_transpose<<<dim3(64, 16, 1), 256, 0, stream>>>(lin1, W1T, DD, EE * ESS);
  k_transpose<<<dim3(16, 4, 16), 256, 0, stream>>>(lin2, W2T, ESS, DD);
  // gating
  k_logits<<<NTOK / 4, 256, 0, stream>>>(x, gate, logits, xb, inv);
  hipMemsetAsync(ghist, 0, (size_t)8 * 1024 * 1024, stream);
  k_hist<<<128, 1024, 0, stream>>>(logits, ghist, separt);
  k_scan64k<<<EE, 1024, 0, stream>>>(ghist, s1, 1, s1, separt, pres);
  k_refine<<<128, 1024, 0, stream>>>(logits, s1, hist2);
  k_scan64k<<<EE, 1024, 0, stream>>>(hist2, s1, 2, s1, separt, pres);
  k_count<<<128, 1024, 0, stream>>>(logits, pres, cnts);
  k_compact<<<128, 1024, 0, stream>>>(logits, pres, cnts, sidx, sval, inv);
  // expert FF
  if (combine) {
    k_ff<<<1024, 512, 0, stream>>>(xb, W1T, W2T, sidx, sval, outbuf);
    k_combine<<<NTOK / 8, 256, 0, stream>>>(outbuf, inv, z);
  } else {
    hipMemsetAsync(d_out, 0, (size_t)out_size * sizeof(float), stream);
    k_gemm1<<<512, 512, 0, stream>>>(xb, W1T, sidx, sval, H);
    k_gemm2_atomic<<<2048, 512, 0, stream>>>(H, W2T, sidx, z);
  }
}

// Round 18
// 312.497 us; speedup vs baseline: 1.0125x; 1.0125x over previous
//
#include <hip/hip_runtime.h>
#include <hip/hip_bf16.h>

#define BB 8
#define CC 4096
#define DD 1024
#define EE 16
#define ESS 256
#define KSEL 4096
#define NTOK (BB*CC)
#define HLS 264   // padded Hl stride (shorts)

typedef short bf16x8 __attribute__((ext_vector_type(8)));
typedef float f32x4 __attribute__((ext_vector_type(4)));
typedef unsigned u32x4 __attribute__((ext_vector_type(4)));

struct PickRes { unsigned tau; unsigned n_gt; unsigned n_tie; float sm; };
struct Sel1 { unsigned b; unsigned above; unsigned kth; };

__device__ __forceinline__ short f2bf(float f) {
  unsigned u = __float_as_uint(f);
  u += 0x7FFFu + ((u >> 16) & 1u);
  return (short)(u >> 16);
}
__device__ __forceinline__ float bf2f(short s) {
  return __uint_as_float(((unsigned)(unsigned short)s) << 16);
}
__device__ __forceinline__ unsigned f2key(float f) {
  unsigned u = __float_as_uint(f);
  return (u & 0x80000000u) ? ~u : (u | 0x80000000u);
}

#define ASG __attribute__((address_space(1)))
#define ASL __attribute__((address_space(3)))
__device__ __forceinline__ void gl_lds16(void* l, const void* g) {
  __builtin_amdgcn_global_load_lds((ASG const unsigned*)g, (ASL unsigned*)l, 16, 0, 0);
}

// ---------------- K1: xsum + logits + x->bf16 conversion + inv init ----------------
__global__ void k_logits(const float* __restrict__ x, const float* __restrict__ gate,
                         float* __restrict__ logits, short* __restrict__ xb,
                         int* __restrict__ inv) {
  int wid = threadIdx.x >> 6, lane = threadIdx.x & 63;
  int t = blockIdx.x * 4 + wid;
  const float4* xr = reinterpret_cast<const float4*>(x + (size_t)t * DD);
  short4* xw = reinterpret_cast<short4*>(xb + (size_t)t * DD);
  float s = 0.f;
#pragma unroll
  for (int i = 0; i < 4; ++i) {
    float4 v = xr[lane + 64 * i];
    s += v.x + v.y + v.z + v.w;
    short4 p;
    p.x = f2bf(v.x); p.y = f2bf(v.y); p.z = f2bf(v.z); p.w = f2bf(v.w);
    xw[lane + 64 * i] = p;
  }
#pragma unroll
  for (int off = 32; off; off >>= 1) s += __shfl_xor(s, off);
  if (lane < EE) {
    int c = t & (CC - 1);
    logits[(size_t)lane * NTOK + t] = s * gate[c * EE + lane];
    inv[(size_t)t * EE + lane] = -1;
  }
}

// ---------------- k_hist ----------------
__global__ __launch_bounds__(1024) void k_hist(const float* __restrict__ logits,
                                               unsigned* __restrict__ ghist,
                                               float* __restrict__ separt) {
  int e = blockIdx.x & 15, seg = blockIdx.x >> 4;
  const float* L = logits + (size_t)e * NTOK + seg * 4096;
  unsigned* Hh = ghist + (size_t)e * 65536;
  int tid = threadIdx.x;
  float sl = 0.f;
#pragma unroll
  for (int i = 0; i < 4; ++i) {
    float lv = L[tid + 1024 * i];
    atomicAdd(&Hh[f2key(lv) >> 16], 1u);
    sl += expf(lv);
  }
  __shared__ float red[1024];
  red[tid] = sl; __syncthreads();
  for (int s2 = 512; s2; s2 >>= 1) {
    if (tid < s2) red[tid] += red[tid + s2];
    __syncthreads();
  }
  if (tid == 0) separt[e * 8 + seg] = red[0];
}

// ---------------- k_scan64k ----------------
__global__ __launch_bounds__(1024) void k_scan64k(
    const unsigned* __restrict__ hist, const Sel1* __restrict__ s1in, int phase,
    Sel1* __restrict__ s1out, const float* __restrict__ separt,
    PickRes* __restrict__ pres) {
  int e = blockIdx.x;
  const unsigned* Hh = hist + (size_t)e * 65536;
  int tid = threadIdx.x;
  __shared__ unsigned u0[1024], u1[1024];
  __shared__ unsigned sh_b, sh_above, sh_kth;
  unsigned target = (phase == 1) ? (unsigned)KSEL : s1in[e].kth;
  unsigned cs = 0;
  for (int j = 0; j < 64; ++j) cs += Hh[tid * 64 + j];
  u0[tid] = cs; __syncthreads();
  unsigned* src = u0; unsigned* dst = u1;
  for (int d2 = 1; d2 < 1024; d2 <<= 1) {
    unsigned v = src[tid] + ((tid + d2 < 1024) ? src[tid + d2] : 0u);
    dst[tid] = v; __syncthreads();
    unsigned* tmp = src; src = dst; dst = tmp;
  }
  unsigned above = (tid < 1023) ? src[tid + 1] : 0u;
  if (above < target && target <= src[tid]) {
    unsigned cum = above;
    for (int j = 63; j >= 0; --j) {
      unsigned h = Hh[tid * 64 + j];
      if (cum + h >= target) { sh_b = (unsigned)(tid * 64 + j); sh_above = cum; sh_kth = target - cum; break; }
      cum += h;
    }
  }
  __syncthreads();
  if (tid == 0) {
    if (phase == 1) {
      Sel1 s; s.b = sh_b; s.above = sh_above; s.kth = sh_kth;
      s1out[e] = s;
    } else {
      unsigned tau = (s1in[e].b << 16) | sh_b;
      unsigned n_gt = s1in[e].above + sh_above;
      float sm = 0.f;
      for (int j = 0; j < 8; ++j) sm += separt[e * 8 + j];
      PickRes pr; pr.tau = tau; pr.n_gt = n_gt; pr.n_tie = KSEL - n_gt; pr.sm = sm;
      pres[e] = pr;
    }
  }
}

// ---------------- k_refine ----------------
__global__ __launch_bounds__(1024) void k_refine(const float* __restrict__ logits,
                                                 const Sel1* __restrict__ s1,
                                                 unsigned* __restrict__ hist2) {
  int e = blockIdx.x & 15, seg = blockIdx.x >> 4;
  unsigned p16 = s1[e].b;
  const float* L = logits + (size_t)e * NTOK + seg * 4096;
  unsigned* Hh = hist2 + (size_t)e * 65536;
  int tid = threadIdx.x;
#pragma unroll
  for (int i = 0; i < 4; ++i) {
    unsigned key = f2key(L[tid + 1024 * i]);
    if ((key >> 16) == p16) atomicAdd(&Hh[key & 0xFFFF], 1u);
  }
}

// ---------------- k_count ----------------
__global__ __launch_bounds__(1024) void k_count(const float* __restrict__ logits,
                                                const PickRes* __restrict__ pres,
                                                unsigned* __restrict__ cnts) {
  int e = blockIdx.x & 15, seg = blockIdx.x >> 4;
  PickRes pr = pres[e];
  const float* L = logits + (size_t)e * NTOK + seg * 4096;
  int tid = threadIdx.x;
  unsigned pk = 0;
#pragma unroll
  for (int i = 0; i < 4; ++i) {
    unsigned key = f2key(L[tid + 1024 * i]);
    pk += (key > pr.tau) ? 0x10000u : ((key == pr.tau) ? 1u : 0u);
  }
  __shared__ unsigned red[1024];
  red[tid] = pk; __syncthreads();
  for (int s2 = 512; s2; s2 >>= 1) {
    if (tid < s2) red[tid] += red[tid + s2];
    __syncthreads();
  }
  if (tid == 0) cnts[e * 8 + seg] = red[0];   // (g<<16)|q
}

// ---------------- k_compact (derives its base from cnts) ----------------
__global__ __launch_bounds__(1024) void k_compact(const float* __restrict__ logits,
                                                  const PickRes* __restrict__ pres,
                                                  const unsigned* __restrict__ cnts,
                                                  int* __restrict__ sel_idx,
                                                  float* __restrict__ sel_val,
                                                  int* __restrict__ inv) {
  int e = blockIdx.x & 15, seg = blockIdx.x >> 4;
  PickRes pr = pres[e];
  const float* L = logits + (size_t)e * NTOK;
  __shared__ unsigned wtg[16], wtq[16];
  __shared__ unsigned base_g, base_q;
  int tid = threadIdx.x, wid = tid >> 6, lane = tid & 63;
  if (tid == 0) {
    unsigned gb = 0, qb = 0;
    for (int s = 0; s < seg; ++s) {
      unsigned c = cnts[e * 8 + s];
      gb += c >> 16; qb += c & 0xFFFFu;
    }
    base_g = gb; base_q = qb;
  }
  __syncthreads();
#pragma unroll 1
  for (int i = 0; i < 4; ++i) {
    int t = seg * 4096 + tid + 1024 * i;
    float lv = L[t];
    unsigned key = f2key(lv);
    bool g = key > pr.tau, q = key == pr.tau;
    unsigned long long bg = __ballot(g), bq = __ballot(q);
    unsigned long long lm = (1ull << lane) - 1ull;
    unsigned pg = __popcll(bg & lm), pq = __popcll(bq & lm);
    if (lane == 63) { wtg[wid] = pg + (g ? 1u : 0u); wtq[wid] = pq + (q ? 1u : 0u); }
    __syncthreads();
    unsigned og = base_g, oq = base_q;
    for (int w2 = 0; w2 < wid; ++w2) { og += wtg[w2]; oq += wtq[w2]; }
    unsigned slot = 0xFFFFFFFFu;
    if (g) slot = og + pg;
    else if (q) {
      unsigned r = oq + pq;
      if (r < pr.n_tie) slot = pr.n_gt + r;
    }
    if (slot != 0xFFFFFFFFu) {
      sel_idx[(size_t)e * KSEL + slot] = t;
      sel_val[(size_t)e * KSEL + slot] = expf(lv) / pr.sm;
      inv[(size_t)t * EE + e] = e * KSEL + (int)slot;
    }
    __syncthreads();
    if (tid == 0) {
      unsigned sg = 0, sq = 0;
#pragma unroll
      for (int w2 = 0; w2 < 16; ++w2) { sg += wtg[w2]; sq += wtq[w2]; }
      base_g += sg; base_q += sq;
    }
    __syncthreads();
  }
}

// ---------------- transpose ----------------
__global__ void k_transpose(const float* __restrict__ src, short* __restrict__ dst,
                            int R, int C) {
  __shared__ float tile[64][65];
  int c0 = blockIdx.x * 64, r0 = blockIdx.y * 64, b = blockIdx.z;
  const float* S = src + (size_t)b * R * C;
  short* Dp = dst + (size_t)b * R * C;
  int tx = threadIdx.x & 63, ty = threadIdx.x >> 6;
#pragma unroll
  for (int i = 0; i < 16; ++i) {
    int r = ty + 4 * i;
    tile[r][tx] = S[(size_t)(r0 + r) * C + c0 + tx];
  }
  __syncthreads();
#pragma unroll
  for (int i = 0; i < 16; ++i) {
    int cR = ty + 4 * i;
    Dp[(size_t)(c0 + cR) * R + r0 + tx] = f2bf(tile[tx][cR]);
  }
}

// ---------------- k_ff: FUSED expert FF, BM=64 (proven R16 structure) ----------------
__global__ __launch_bounds__(512, 2) void k_ff(
    const short* __restrict__ xb, const short* __restrict__ W1T,
    const short* __restrict__ W2T, const int* __restrict__ sel_idx,
    const float* __restrict__ sel_val, short* __restrict__ out) {
  int bid = blockIdx.x;
  int e = (bid & 7) + ((bid >> 9) << 3);      // expert -> XCD affinity
  int m0 = ((bid >> 3) & 63) * 64;
  __shared__ short Hl[64 * HLS];              // 33 KB, padded stride
  __shared__ bf16x8 As8[64 * 8];              // 8 KB
  __shared__ bf16x8 Bs8[256 * 8];             // 32 KB (W1 then W2 staging)
  int tid = threadIdx.x, lane = tid & 63, wid = tid >> 6;
  int wr = wid >> 2, wc = wid & 3;            // 2 x 4 waves, wave tile 32x64
  const int* idxE = sel_idx + (size_t)e * KSEL;
  f32x4 acc[2][4] = {};

  int rowA = tid >> 3, sA = tid & 7;
  int xk = rowA & 7;
  const short* aSrc = xb + (size_t)idxE[m0 + rowA] * DD + (sA ^ xk) * 8;
  const short* w1Base = W1T + (size_t)e * ESS * DD + (size_t)rowA * DD + (sA ^ xk) * 8;
  const short* w2Base = W2T + (size_t)e * DD * ESS + (size_t)rowA * ESS + (sA ^ xk) * 8;

  // ---- phase 1: K = DD = 1024, 16 steps ----
  for (int kt = 0; kt < DD / 64; ++kt) {
    int kofs = kt * 64;
    gl_lds16(&As8[tid], aSrc + kofs);
#pragma unroll
    for (int j = 0; j < 4; ++j)
      gl_lds16(&Bs8[j * 512 + tid], w1Base + (size_t)(64 * j) * DD + kofs);
    __syncthreads();
    bf16x8 af[2][2];
#pragma unroll
    for (int mg = 0; mg < 2; ++mg) {
      int row = wr * 32 + mg * 16 + (lane & 15);
#pragma unroll
      for (int h = 0; h < 2; ++h) {
        int seg = h * 4 + (lane >> 4);
        af[mg][h] = As8[row * 8 + (seg ^ (row & 7))];
      }
    }
#pragma unroll
    for (int ng = 0; ng < 4; ++ng) {
      int rowb = wc * 64 + ng * 16 + (lane & 15);
      bf16x8 b0 = Bs8[rowb * 8 + (((lane >> 4) + 0) ^ (rowb & 7))];
      bf16x8 b1 = Bs8[rowb * 8 + (((lane >> 4) + 4) ^ (rowb & 7))];
#pragma unroll
      for (int mg = 0; mg < 2; ++mg) {
        acc[mg][ng] = __builtin_amdgcn_mfma_f32_16x16x32_bf16(af[mg][0], b0, acc[mg][ng], 0, 0, 0);
        acc[mg][ng] = __builtin_amdgcn_mfma_f32_16x16x32_bf16(af[mg][1], b1, acc[mg][ng], 0, 0, 0);
      }
    }
    __syncthreads();
  }
  // ---- prestage W2 (stage 0) while writing Hl ----
#pragma unroll
  for (int j = 0; j < 4; ++j)
    gl_lds16(&Bs8[j * 512 + tid], w2Base + (size_t)(64 * j) * ESS);
  // ---- H tile -> LDS (relu * val), padded stride ----
#pragma unroll
  for (int mg = 0; mg < 2; ++mg) {
#pragma unroll
    for (int r = 0; r < 4; ++r) {
      int hrow = wr * 32 + mg * 16 + (lane >> 4) * 4 + r;
      float v = sel_val[(size_t)e * KSEL + m0 + hrow];
#pragma unroll
      for (int ng = 0; ng < 4; ++ng) {
        int col = wc * 64 + ng * 16 + (lane & 15);
        Hl[hrow * HLS + col] = f2bf(fmaxf(acc[mg][ng][r], 0.f) * v);
      }
    }
  }
  __syncthreads();   // Hl visible + stage(0) landed (barrier drains vmcnt)
  // ---- phase 2: 16 flattened stages (np = s>>2, kt = s&3); out-write overlaps staging ----
  f32x4 acc2[2][4] = {};
#pragma unroll 1
  for (int s = 0; s < 16; ++s) {
    int kt = s & 3;
    bf16x8 af[2][2];
#pragma unroll
    for (int mg = 0; mg < 2; ++mg) {
      int row = wr * 32 + mg * 16 + (lane & 15);
#pragma unroll
      for (int h = 0; h < 2; ++h) {
        int s8 = h * 4 + (lane >> 4);
        af[mg][h] = *reinterpret_cast<const bf16x8*>(&Hl[row * HLS + kt * 64 + s8 * 8]);
      }
    }
#pragma unroll
    for (int ng = 0; ng < 4; ++ng) {
      int rowb = wc * 64 + ng * 16 + (lane & 15);
      bf16x8 b0 = Bs8[rowb * 8 + (((lane >> 4) + 0) ^ (rowb & 7))];
      bf16x8 b1 = Bs8[rowb * 8 + (((lane >> 4) + 4) ^ (rowb & 7))];
#pragma unroll
      for (int mg = 0; mg < 2; ++mg) {
        acc2[mg][ng] = __builtin_amdgcn_mfma_f32_16x16x32_bf16(af[mg][0], b0, acc2[mg][ng], 0, 0, 0);
        acc2[mg][ng] = __builtin_amdgcn_mfma_f32_16x16x32_bf16(af[mg][1], b1, acc2[mg][ng], 0, 0, 0);
      }
    }
    __syncthreads();                       // all waves done reading Bs8
    if (s < 15) {                          // issue next W2 stage
      int s2 = s + 1;
      int np2 = s2 >> 2, kt2 = s2 & 3;
#pragma unroll
      for (int j = 0; j < 4; ++j)
        gl_lds16(&Bs8[j * 512 + tid],
                 w2Base + (size_t)(np2 * 256 + 64 * j) * ESS + kt2 * 64);
    }
    if (kt == 3) {                         // n-panel done: write out (overlaps stage)
      int np = s >> 2;
      int n0 = np * 256;
#pragma unroll
      for (int mg = 0; mg < 2; ++mg) {
#pragma unroll
        for (int r = 0; r < 4; ++r) {
          int ml = wr * 32 + mg * 16 + (lane >> 4) * 4 + r;
          short* orow = out + ((size_t)(e * KSEL + m0 + ml)) * DD + n0 + wc * 64 + (lane & 15);
#pragma unroll
          for (int ng = 0; ng < 4; ++ng) orow[ng * 16] = f2bf(acc2[mg][ng][r]);
        }
      }
#pragma unroll
      for (int mg = 0; mg < 2; ++mg)
#pragma unroll
        for (int ng = 0; ng < 4; ++ng) {
          f32x4 zz = {0.f, 0.f, 0.f, 0.f};
          acc2[mg][ng] = zz;
        }
    }
    if (s < 15) __syncthreads();           // next stage landed
  }
}

// ---------------- fallback GEMMs (atomic path, used only if workspace too small) ----------------
__global__ __launch_bounds__(512, 4) void k_gemm1(
    const short* __restrict__ xb, const short* __restrict__ W1T,
    const int* __restrict__ sel_idx, const float* __restrict__ sel_val,
    short* __restrict__ H) {
  int bid = blockIdx.x;
  int m0 = ((bid >> 3) & 31) * 128;
  int e = (bid & 7) + ((bid >> 8) << 3);
  __shared__ bf16x8 As8[128 * 8];
  __shared__ bf16x8 Bs8[256 * 8];
  int tid = threadIdx.x, lane = tid & 63, wid = tid >> 6;
  int wr = wid >> 2, wc = wid & 3;
  const int* idxE = sel_idx + (size_t)e * KSEL;
  f32x4 acc[4][4] = {};

  int rowA = tid >> 3, sA = tid & 7;
  int xk = rowA & 7;
  const short* aSrc0 = xb + (size_t)idxE[m0 + rowA] * DD + (sA ^ xk) * 8;
  const short* aSrc1 = xb + (size_t)idxE[m0 + rowA + 64] * DD + (sA ^ xk) * 8;
  const short* wBase = W1T + (size_t)e * ESS * DD + (size_t)rowA * DD + (sA ^ xk) * 8;

  for (int kt = 0; kt < DD / 64; ++kt) {
    int kofs = kt * 64;
    gl_lds16(&As8[tid], aSrc0 + kofs);
    gl_lds16(&As8[512 + tid], aSrc1 + kofs);
#pragma unroll
    for (int j = 0; j < 4; ++j)
      gl_lds16(&Bs8[j * 512 + tid], wBase + (size_t)(64 * j) * DD + kofs);
    __syncthreads();
    bf16x8 af[4][2];
#pragma unroll
    for (int mg = 0; mg < 4; ++mg) {
      int row = wr * 64 + mg * 16 + (lane & 15);
#pragma unroll
      for (int h = 0; h < 2; ++h) {
        int seg = h * 4 + (lane >> 4);
        af[mg][h] = As8[row * 8 + (seg ^ (row & 7))];
      }
    }
#pragma unroll
    for (int ng = 0; ng < 4; ++ng) {
      int rowb = wc * 64 + ng * 16 + (lane & 15);
      bf16x8 b0 = Bs8[rowb * 8 + (((lane >> 4) + 0) ^ (rowb & 7))];
      bf16x8 b1 = Bs8[rowb * 8 + (((lane >> 4) + 4) ^ (rowb & 7))];
#pragma unroll
      for (int mg = 0; mg < 4; ++mg) {
        acc[mg][ng] = __builtin_amdgcn_mfma_f32_16x16x32_bf16(af[mg][0], b0, acc[mg][ng], 0, 0, 0);
        acc[mg][ng] = __builtin_amdgcn_mfma_f32_16x16x32_bf16(af[mg][1], b1, acc[mg][ng], 0, 0, 0);
      }
    }
    __syncthreads();
  }
#pragma unroll
  for (int mg = 0; mg < 4; ++mg) {
#pragma unroll
    for (int r = 0; r < 4; ++r) {
      int ml = wr * 64 + mg * 16 + (lane >> 4) * 4 + r;
      float v = sel_val[(size_t)e * KSEL + m0 + ml];
      short* hrow = H + ((size_t)(e * KSEL + m0 + ml)) * ESS + wc * 64 + (lane & 15);
#pragma unroll
      for (int ng = 0; ng < 4; ++ng) {
        float o = fmaxf(acc[mg][ng][r], 0.f) * v;
        hrow[ng * 16] = f2bf(o);
      }
    }
  }
}

__global__ __launch_bounds__(512, 4) void k_gemm2_atomic(
    const short* __restrict__ H, const short* __restrict__ W2T,
    const int* __restrict__ sel_idx, float* __restrict__ z) {
  int bid = blockIdx.x;
  int p = (bid & 7) + ((bid >> 8) << 3);
  int m0 = ((bid >> 3) & 31) * 128;
  int n0 = (p & 3) * 256;
  int e = p >> 2;
  __shared__ bf16x8 As8[128 * 8];
  __shared__ bf16x8 Bs8[256 * 8];
  int tid = threadIdx.x, lane = tid & 63, wid = tid >> 6;
  int wr = wid >> 2, wc = wid & 3;
  f32x4 acc[4][4] = {};

  int rowA = tid >> 3, sA = tid & 7;
  int xk = rowA & 7;
  const short* hBase = H + (size_t)(e * KSEL + m0 + rowA) * ESS + (sA ^ xk) * 8;
  const short* w2Base = W2T + (size_t)(e * DD + n0 + rowA) * ESS + (sA ^ xk) * 8;

  for (int kt = 0; kt < ESS / 64; ++kt) {
    int kofs = kt * 64;
    gl_lds16(&As8[tid], hBase + kofs);
    gl_lds16(&As8[512 + tid], hBase + (size_t)64 * ESS + kofs);
#pragma unroll
    for (int j = 0; j < 4; ++j)
      gl_lds16(&Bs8[j * 512 + tid], w2Base + (size_t)(64 * j) * ESS + kofs);
    __syncthreads();
    bf16x8 af[4][2];
#pragma unroll
    for (int mg = 0; mg < 4; ++mg) {
      int row = wr * 64 + mg * 16 + (lane & 15);
#pragma unroll
      for (int h = 0; h < 2; ++h) {
        int seg = h * 4 + (lane >> 4);
        af[mg][h] = As8[row * 8 + (seg ^ (row & 7))];
      }
    }
#pragma unroll
    for (int ng = 0; ng < 4; ++ng) {
      int rowb = wc * 64 + ng * 16 + (lane & 15);
      bf16x8 b0 = Bs8[rowb * 8 + (((lane >> 4) + 0) ^ (rowb & 7))];
      bf16x8 b1 = Bs8[rowb * 8 + (((lane >> 4) + 4) ^ (rowb & 7))];
#pragma unroll
      for (int mg = 0; mg < 4; ++mg) {
        acc[mg][ng] = __builtin_amdgcn_mfma_f32_16x16x32_bf16(af[mg][0], b0, acc[mg][ng], 0, 0, 0);
        acc[mg][ng] = __builtin_amdgcn_mfma_f32_16x16x32_bf16(af[mg][1], b1, acc[mg][ng], 0, 0, 0);
      }
    }
    __syncthreads();
  }
#pragma unroll
  for (int mg = 0; mg < 4; ++mg) {
#pragma unroll
    for (int r = 0; r < 4; ++r) {
      int ml = wr * 64 + mg * 16 + (lane >> 4) * 4 + r;
      int token = sel_idx[(size_t)e * KSEL + m0 + ml];
      float* zr = z + (size_t)token * DD + n0 + wc * 64 + (lane & 15);
#pragma unroll
      for (int ng = 0; ng < 4; ++ng) atomicAdd(zr + ng * 16, acc[mg][ng][r]);
    }
  }
}

// ---------------- combine: 2 tokens per wave ----------------
__global__ __launch_bounds__(256) void k_combine(const short* __restrict__ out,
                                                 const int* __restrict__ inv,
                                                 float* __restrict__ z) {
  int wid = threadIdx.x >> 6, lane = threadIdx.x & 63;
  int tA = (blockIdx.x * 4 + wid) * 2;
  int tB = tA + 1;
  int gA[16], gB[16];
  const int4* ivA = reinterpret_cast<const int4*>(inv + (size_t)tA * EE);
  const int4* ivB = reinterpret_cast<const int4*>(inv + (size_t)tB * EE);
#pragma unroll
  for (int q = 0; q < 4; ++q) {
    int4 va = ivA[q];
    gA[4 * q] = va.x; gA[4 * q + 1] = va.y; gA[4 * q + 2] = va.z; gA[4 * q + 3] = va.w;
    int4 vb = ivB[q];
    gB[4 * q] = vb.x; gB[4 * q + 1] = vb.y; gB[4 * q + 2] = vb.z; gB[4 * q + 3] = vb.w;
  }
  float accA[16] = {}, accB[16] = {};
#pragma unroll
  for (int e = 0; e < EE; ++e) {
    if (gA[e] >= 0) {
      const u32x4* rp = reinterpret_cast<const u32x4*>(out + (size_t)gA[e] * DD + lane * 16);
      u32x4 v0 = rp[0], v1 = rp[1];
      const short* s0 = reinterpret_cast<const short*>(&v0);
      const short* s1 = reinterpret_cast<const short*>(&v1);
#pragma unroll
      for (int i = 0; i < 8; ++i) { accA[i] += bf2f(s0[i]); accA[8 + i] += bf2f(s1[i]); }
    }
    if (gB[e] >= 0) {
      const u32x4* rp = reinterpret_cast<const u32x4*>(out + (size_t)gB[e] * DD + lane * 16);
      u32x4 v0 = rp[0], v1 = rp[1];
      const short* s0 = reinterpret_cast<const short*>(&v0);
      const short* s1 = reinterpret_cast<const short*>(&v1);
#pragma unroll
      for (int i = 0; i < 8; ++i) { accB[i] += bf2f(s0[i]); accB[8 + i] += bf2f(s1[i]); }
    }
  }
  float4* zwA = reinterpret_cast<float4*>(z + (size_t)tA * DD + lane * 16);
  float4* zwB = reinterpret_cast<float4*>(z + (size_t)tB * DD + lane * 16);
#pragma unroll
  for (int i = 0; i < 4; ++i) {
    float4 oa;
    oa.x = accA[4 * i]; oa.y = accA[4 * i + 1]; oa.z = accA[4 * i + 2]; oa.w = accA[4 * i + 3];
    zwA[i] = oa;
    float4 ob;
    ob.x = accB[4 * i]; ob.y = accB[4 * i + 1]; ob.z = accB[4 * i + 2]; ob.w = accB[4 * i + 3];
    zwB[i] = ob;
  }
}

extern "C" void kernel_launch(void* const* d_in, const int* in_sizes, int n_in,
                              void* d_out, int out_size, void* d_ws, size_t ws_size,
                              hipStream_t stream) {
  (void)in_sizes; (void)n_in;
  const float* x = (const float*)d_in[0];
  const float* gate = (const float*)d_in[1];
  const float* lin1 = (const float*)d_in[2];
  const float* lin2 = (const float*)d_in[3];
  float* z = (float*)d_out;

  char* ws = (char*)d_ws;
  size_t off = 0;
  auto alloc = [&](size_t bytes) -> void* {
    off = (off + 255) & ~(size_t)255;
    void* p = ws + off;
    off += bytes;
    return p;
  };
  float* logits = (float*)alloc((size_t)EE * NTOK * 4);
  int* sidx = (int*)alloc((size_t)EE * KSEL * 4);
  float* sval = (float*)alloc((size_t)EE * KSEL * 4);
  int* inv = (int*)alloc((size_t)NTOK * EE * 4);
  short* W1T = (short*)alloc((size_t)EE * ESS * DD * 2);
  short* W2T = (short*)alloc((size_t)EE * DD * ESS * 2);
  short* H = (short*)alloc((size_t)EE * KSEL * ESS * 2);
  short* xb = (short*)alloc((size_t)NTOK * DD * 2);
  size_t out_bytes = (size_t)EE * KSEL * DD * 2;
  bool combine = (off + 256 + out_bytes) <= ws_size;
  short* outbuf = combine ? (short*)alloc(out_bytes) : nullptr;

  // select scratch aliases H (H is only used by the fallback path, after select)
  unsigned* ghist = (unsigned*)H;                                    // 4 MB
  unsigned* hist2 = (unsigned*)((char*)H + (size_t)4 * 1024 * 1024); // 4 MB
  float* separt = (float*)((char*)H + (size_t)8 * 1024 * 1024);      // 512 B
  Sel1* s1 = (Sel1*)((char*)separt + 1024);                          // 256 B
  PickRes* pres = (PickRes*)((char*)s1 + 1024);                      // 256 B
  unsigned* cnts = (unsigned*)((char*)pres + 1024);                  // 512 B

  // weight transposes
  k_transpose<<<dim3(64, 16, 1), 256, 0, stream>>>(lin1, W1T, DD, EE * ESS);
  k_transpose<<<dim3(16, 4, 16), 256, 0, stream>>>(lin2, W2T, ESS, DD);
  // gating
  k_logits<<<NTOK / 4, 256, 0, stream>>>(x, gate, logits, xb, inv);
  hipMemsetAsync(ghist, 0, (size_t)8 * 1024 * 1024, stream);
  k_hist<<<128, 1024, 0, stream>>>(logits, ghist, separt);
  k_scan64k<<<EE, 1024, 0, stream>>>(ghist, s1, 1, s1, separt, pres);
  k_refine<<<128, 1024, 0, stream>>>(logits, s1, hist2);
  k_scan64k<<<EE, 1024, 0, stream>>>(hist2, s1, 2, s1, separt, pres);
  k_count<<<128, 1024, 0, stream>>>(logits, pres, cnts);
  k_compact<<<128, 1024, 0, stream>>>(logits, pres, cnts, sidx, sval, inv);
  // expert FF
  if (combine) {
    k_ff<<<1024, 512, 0, stream>>>(xb, W1T, W2T, sidx, sval, outbuf);
    k_combine<<<NTOK / 8, 256, 0, stream>>>(outbuf, inv, z);
  } else {
    hipMemsetAsync(d_out, 0, (size_t)out_size * sizeof(float), stream);
    k_gemm1<<<512, 512, 0, stream>>>(xb, W1T, sidx, sval, H);
    k_gemm2_atomic<<<2048, 512, 0, stream>>>(H, W2T, sidx, z);
  }
}